// Round 9
// baseline (230.078 us; speedup 1.0000x reference)
//
#include <hip/hip_runtime.h>
#include <math.h>

#ifndef __has_builtin
#define __has_builtin(x) 0
#endif

__device__ __forceinline__ float fsqrt(float x){
#if __has_builtin(__builtin_amdgcn_sqrtf)
    return __builtin_amdgcn_sqrtf(x);
#else
    return sqrtf(x);
#endif
}
__device__ __forceinline__ float frsqrt(float x){
#if __has_builtin(__builtin_amdgcn_rsqf)
    return __builtin_amdgcn_rsqf(x);
#else
    return 1.0f/sqrtf(x);
#endif
}
__device__ __forceinline__ float frcp(float x){
#if __has_builtin(__builtin_amdgcn_rcpf)
    return __builtin_amdgcn_rcpf(x);
#else
    return 1.0f/x;
#endif
}

namespace {
constexpr int TT = 256;
constexpr int BB = 16384;
constexpr float DT  = 0.05f, CD = 0.25f, AP = 0.1f, AV = 0.1f;
constexpr float CJ  = 2.56e-6f;              // CUT*JIT
constexpr float CVV = 1.0f - DT*CD;          // 0.9875
constexpr float WC0 = 1.7975f;
constexpr float W2  = 0.390625f;             // 2*WI ; CUT*W2 == 1.0 exactly
constexpr float WA  = 2.57875f;              // WC0 + 4WI
constexpr float WAC = 6.6016f;               // CUT*WA
constexpr float WCC = 4.6016f;               // CUT*WC0
constexpr float W2E = 0.1171875f;            // W2*0.3
constexpr float RSG = 0.00640512f;           // CUT*(Rd + 2*JIT)
constexpr float CQ2C = 1.53125f;             // CUT*CQ2
constexpr float CB00 = 3.072e-5f;            // CUT*(Q00 + 2JIT)
constexpr float CB11 = 2.6112e-4f;           // CUT*(Q11 + 2JIT)
constexpr float CB22 = 1.024e-5f;            // CUT*(predJIT + Q22 + 2JIT)
constexpr float HCUT = 1.28f;                // 0.5*CUT
constexpr float CUTc = 2.56f;
}

// ---------------- flat-scalar per-filter state (no struct: R8's struct form
// kept ~100MB of scratch writebacks even at VGPR=132; flat locals + deferred
// B' computation shrink cross-phase live ranges below the budget) -----------

#define DECL(S) \
  float S##_z0,S##_z1,S##_z2,S##_z3, \
        S##_P00,S##_P01,S##_P02,S##_P03,S##_P11,S##_P12,S##_P13,S##_P22,S##_P23,S##_P33, \
        S##_g00,S##_g10,S##_g20,S##_g30,S##_g11,S##_g21,S##_g31,S##_g22,S##_g32,S##_g33, \
        S##_X00,S##_X01,S##_Xp,S##_Xm,S##_D10,S##_q,S##_D00,S##_D01,S##_D11,S##_D12,S##_D13, \
        S##_yn0,S##_yn1,S##_un; \
  const float *S##_yb, *S##_ub; float *S##_ob;

#define LOAD(S, bidx) { \
  const int b_ = (bidx); \
  S##_z0 = z0g[b_*4+0]; S##_z1 = z0g[b_*4+1]; S##_z2 = z0g[b_*4+2]; S##_z3 = z0g[b_*4+3]; \
  const float* Pb_ = P0g + (size_t)b_*16; \
  S##_P00 = CUTc*Pb_[0]; \
  S##_P01 = HCUT*(Pb_[1]+Pb_[4]); \
  S##_P02 = HCUT*(Pb_[2]+Pb_[8]); \
  S##_P03 = HCUT*(Pb_[3]+Pb_[12]); \
  S##_P11 = CUTc*Pb_[5]; \
  S##_P12 = HCUT*(Pb_[6]+Pb_[9]); \
  S##_P13 = HCUT*(Pb_[7]+Pb_[13]); \
  S##_P22 = CUTc*Pb_[10]; \
  S##_P23 = HCUT*(Pb_[11]+Pb_[14]); \
  S##_P33 = CUTc*Pb_[15]; \
  S##_yb = yg + (size_t)b_*TT*2; \
  S##_ub = ug + (size_t)b_*TT; \
  S##_ob = outg + (size_t)b_*TT*4; }

// G = chol(Pc + CJ*I)
#define CHOL(S) { \
  float a00_ = S##_P00 + CJ; \
  float r0_  = frsqrt(a00_); \
  S##_g00 = a00_*r0_; \
  S##_g10 = S##_P01*r0_; \
  S##_g20 = S##_P02*r0_; \
  S##_g30 = S##_P03*r0_; \
  float a11_ = fmaf(-S##_g10,S##_g10, S##_P11 + CJ); \
  float r1_  = frsqrt(a11_); \
  S##_g11 = a11_*r1_; \
  S##_g21 = fmaf(-S##_g20,S##_g10, S##_P12)*r1_; \
  S##_g31 = fmaf(-S##_g30,S##_g10, S##_P13)*r1_; \
  float a22_ = fmaf(-S##_g21,S##_g21, fmaf(-S##_g20,S##_g20, S##_P22 + CJ)); \
  float r2_  = frsqrt(a22_); \
  S##_g22 = a22_*r2_; \
  S##_g32 = fmaf(-S##_g31,S##_g21, fmaf(-S##_g30,S##_g20, S##_P23))*r2_; \
  float a33_ = fmaf(-S##_g32,S##_g32, fmaf(-S##_g31,S##_g31, fmaf(-S##_g30,S##_g30, S##_P33 + CJ))); \
  S##_g33 = fsqrt(a33_); }

#define PRED0(S) { \
  S##_X00=S##_z0; S##_X01=S##_z1; \
  S##_Xp=S##_z1+S##_g10; S##_Xm=S##_z1-S##_g10; \
  S##_D10=S##_g10; S##_q=0.0f; \
  S##_D00=S##_g00; S##_D01=0.0f; S##_D11=S##_g11; S##_D12=0.0f; S##_D13=0.0f; }

#define PRED(S, uu) { \
  float w_  = S##_z0*S##_z0; \
  float zc_ = w_*S##_z0; \
  S##_X00 = fmaf(DT, S##_z1, S##_z0); \
  float ac_ = fmaf(-CD, S##_z1, (uu)); \
  ac_ = fmaf(-S##_z2, S##_z0, ac_); \
  ac_ = fmaf(-S##_z3, zc_, ac_); \
  S##_X01 = fmaf(DT, ac_, S##_z1); \
  float pp_ = S##_z0+S##_g00, pm_ = S##_z0-S##_g00; \
  float vp_ = S##_z1+S##_g10, vm_ = S##_z1-S##_g10; \
  float kp_ = S##_z2+S##_g20, km_ = S##_z2-S##_g20; \
  float aP_ = S##_z3+S##_g30, aM_ = S##_z3-S##_g30; \
  float cp3_ = (pp_*pp_)*pp_, cm3_ = (pm_*pm_)*pm_; \
  float accp_ = fmaf(-CD, vp_, (uu)); accp_ = fmaf(-kp_,pp_,accp_); accp_ = fmaf(-aP_,cp3_,accp_); \
  S##_Xp = fmaf(DT, accp_, vp_); \
  float accm_ = fmaf(-CD, vm_, (uu)); accm_ = fmaf(-km_,pm_,accm_); accm_ = fmaf(-aM_,cm3_,accm_); \
  S##_Xm = fmaf(DT, accm_, vm_); \
  S##_D10 = 0.5f*(S##_Xp - S##_Xm); \
  S##_q   = fmaf(0.5f, S##_Xp + S##_Xm, -S##_X01); \
  S##_D00 = fmaf(DT, S##_g10, S##_g00); \
  S##_D01 = DT*S##_g11; \
  float ha_ = fmaf(S##_g31, zc_, S##_g21*S##_z0); \
  S##_D11 = fmaf(CVV, S##_g11, -(DT*ha_)); \
  float hb_ = fmaf(S##_g32, zc_, S##_g22*S##_z0); \
  S##_D12 = -(DT*hb_); \
  S##_D13 = -(DT*(S##_g33*zc_)); }

// Measurement update; B' computed INLINE in the P_post epilogue (deferred from
// predict: halves cross-phase live values). QA/QB/QC are the diag constants
// (CJ,CJ,CJ at t=0; CB00,CB11,CB22 in the main loop) — with t=0's D-values the
// same B' formulas reproduce Pc exactly via the Cholesky identity.
#define UPDATE(S, y0, y1, QA, QB, QC) { \
  float eps_c = -W2*S##_q; \
  float eps_a = S##_q + eps_c; \
  float zp1 = fmaf(W2, S##_q, S##_X01); \
  float w0 = S##_X00*S##_X00, w1 = S##_X01*S##_X01; \
  float apx = AP*S##_X00, avx = AV*S##_X01; \
  float Y00 = fmaf(apx, w0, S##_X00); \
  float Y01 = fmaf(avx, w1, S##_X01); \
  float cp = fmaf(0.3f, w0, 1.0f); \
  float cv = fmaf(0.3f, w1, 1.0f); \
  float e3p = 0.3f*S##_X00, e3v = 0.3f*S##_X01; \
  float w2e3p = W2E*S##_X00; \
  float D00sq = S##_D00*S##_D00, D01sq = S##_D01*S##_D01; \
  float SD0 = D00sq + D01sq; \
  float yp0 = fmaf(w2e3p, SD0, Y00); \
  float ec0 = Y00 - yp0; \
  float xi0 = fmaf(e3p, D00sq, ec0); \
  float xi1 = fmaf(e3p, D01sq, ec0); \
  float Od00 = S##_D00*fmaf(AP, D00sq, cp); \
  float Od01 = S##_D01*fmaf(AP, D01sq, cp); \
  float sp = S##_Xp*S##_Xp, sm = S##_Xm*S##_Xm; \
  float Yp = fmaf(AV*S##_Xp, sp, S##_Xp); \
  float Ym = fmaf(AV*S##_Xm, sm, S##_Xm); \
  float qy = fmaf(0.5f, Yp + Ym, -Y01); \
  float Q0 = 0.5f*(Yp - Ym); \
  float D11sq = S##_D11*S##_D11, D12sq = S##_D12*S##_D12, D13sq = S##_D13*S##_D13; \
  float SD1 = (D11sq + D12sq) + D13sq; \
  float inner = fmaf(e3v, SD1, qy); \
  float yp1 = fmaf(W2, inner, Y01); \
  float ec1 = Y01 - yp1; \
  float et0 = qy + ec1; \
  float et1 = fmaf(e3v, D11sq, ec1); \
  float et2 = fmaf(e3v, D12sq, ec1); \
  float et3 = fmaf(e3v, D13sq, ec1); \
  float Q1 = S##_D11*fmaf(AV, D11sq, cv); \
  float Q2 = S##_D12*fmaf(AV, D12sq, cv); \
  float Q3 = S##_D13*fmaf(AV, D13sq, cv); \
  float et23 = et2 + et3; \
  float Ts00 = fmaf(Od00,Od00, xi0*xi0); \
  Ts00 = fmaf(xi1,xi1,Ts00); Ts00 = fmaf(Od01,Od01,Ts00); \
  float s00 = fmaf(WAC, ec0*ec0, Ts00); \
  float Ts01 = fmaf(Od00, Q0, xi0*et0); \
  Ts01 = fmaf(xi1, et1, Ts01); Ts01 = fmaf(Od01, Q1, Ts01); \
  Ts01 = fmaf(ec0, et23, Ts01); \
  float s01 = fmaf(WCC, ec0*ec1, Ts01); \
  float Ts11 = fmaf(Q0,Q0, et0*et0); \
  Ts11 = fmaf(et1,et1,Ts11); Ts11 = fmaf(Q1,Q1,Ts11); \
  Ts11 = fmaf(et2,et2,Ts11); Ts11 = fmaf(Q2,Q2,Ts11); \
  Ts11 = fmaf(et3,et3,Ts11); Ts11 = fmaf(Q3,Q3,Ts11); \
  float s11 = fmaf(WCC, ec1*ec1, Ts11); \
  float pz00 = fmaf(S##_D01, Od01, S##_D00*Od00); \
  float pz01 = fmaf(S##_D01, Q1, S##_D00*Q0); \
  float Tp10 = fmaf(S##_D10, Od00, eps_a*xi0); \
  Tp10 = fmaf(eps_c, xi1, Tp10); Tp10 = fmaf(S##_D11, Od01, Tp10); \
  float pz10 = fmaf(-WA, S##_q*ec0, Tp10); \
  float et123 = et1 + et23; \
  float Tp11 = fmaf(S##_D10, Q0, eps_a*et0); \
  Tp11 = fmaf(eps_c, et123, Tp11); \
  Tp11 = fmaf(S##_D11, Q1, Tp11); \
  Tp11 = fmaf(S##_D12, Q2, Tp11); \
  Tp11 = fmaf(S##_D13, Q3, Tp11); \
  float pz11 = fmaf(-WC0, S##_q*ec1, Tp11); \
  float pz20 = fmaf(S##_g21, Od01, S##_g20*Od00); \
  float pz30 = fmaf(S##_g31, Od01, S##_g30*Od00); \
  float pz21 = fmaf(S##_g21, Q1, S##_g20*Q0); pz21 = fmaf(S##_g22, Q2, pz21); \
  float pz31 = fmaf(S##_g31, Q1, S##_g30*Q0); pz31 = fmaf(S##_g32, Q2, pz31); \
  pz31 = fmaf(S##_g33, Q3, pz31); \
  float sg00 = s00 + RSG, sg11 = s11 + RSG; \
  float det = fmaf(sg00, sg11, -(s01*s01)); \
  float idet = frcp(det); \
  float i00 = sg11*idet, i01 = -(s01*idet), i11 = sg00*idet; \
  float K00 = fmaf(pz01,i01, pz00*i00), K01 = fmaf(pz01,i11, pz00*i01); \
  float K10 = fmaf(pz11,i01, pz10*i00), K11 = fmaf(pz11,i11, pz10*i01); \
  float K20 = fmaf(pz21,i01, pz20*i00), K21 = fmaf(pz21,i11, pz20*i01); \
  float K30 = fmaf(pz31,i01, pz30*i00), K31 = fmaf(pz31,i11, pz30*i01); \
  float nu0 = (y0) - yp0, nu1 = (y1) - yp1; \
  S##_z0 = fmaf(K00,nu0, fmaf(K01,nu1, S##_X00)); \
  S##_z1 = fmaf(K10,nu0, fmaf(K11,nu1, zp1)); \
  S##_z2 = fmaf(K20,nu0, fmaf(K21,nu1, S##_z2)); \
  S##_z3 = fmaf(K30,nu0, fmaf(K31,nu1, S##_z3)); \
  float B00p = fmaf(S##_D01,S##_D01, fmaf(S##_D00,S##_D00, (QA))); \
  S##_P00 = fmaf(-K00,pz00, fmaf(-K01,pz01, B00p)); \
  float B01p = fmaf(S##_D01, S##_D11, S##_D00*S##_D10); \
  S##_P01 = fmaf(-K00,pz10, fmaf(-K01,pz11, B01p)); \
  float B02p = fmaf(S##_D01, S##_g21, S##_D00*S##_g20); \
  S##_P02 = fmaf(-K00,pz20, fmaf(-K01,pz21, B02p)); \
  float B03p = fmaf(S##_D01, S##_g31, S##_D00*S##_g30); \
  S##_P03 = fmaf(-K00,pz30, fmaf(-K01,pz31, B03p)); \
  float TB11 = fmaf(S##_D10,S##_D10, (QB)); \
  TB11 = fmaf(S##_D11,S##_D11,TB11); TB11 = fmaf(S##_D12,S##_D12,TB11); TB11 = fmaf(S##_D13,S##_D13,TB11); \
  float B11p = fmaf(CQ2C, S##_q*S##_q, TB11); \
  S##_P11 = fmaf(-K10,pz10, fmaf(-K11,pz11, B11p)); \
  float B12p = fmaf(S##_D11,S##_g21, S##_D10*S##_g20); B12p = fmaf(S##_D12,S##_g22,B12p); \
  S##_P12 = fmaf(-K10,pz20, fmaf(-K11,pz21, B12p)); \
  float B13p = fmaf(S##_D11,S##_g31, S##_D10*S##_g30); B13p = fmaf(S##_D12,S##_g32,B13p); B13p = fmaf(S##_D13,S##_g33,B13p); \
  S##_P13 = fmaf(-K10,pz30, fmaf(-K11,pz31, B13p)); \
  S##_P22 = fmaf(-K20,pz20, fmaf(-K21,pz21, S##_P22 + (QC))); \
  S##_P23 = fmaf(-K20,pz30, fmaf(-K21,pz31, S##_P23)); \
  S##_P33 = fmaf(-K30,pz30, fmaf(-K31,pz31, S##_P33 + (QC))); }

#define STOREZ(S, t) { \
  *reinterpret_cast<float4*>(S##_ob + 4*(t)) = make_float4(S##_z0,S##_z1,S##_z2,S##_z3); }

__global__
__attribute__((amdgpu_flat_work_group_size(64, 64)))
__attribute__((amdgpu_waves_per_eu(1, 1)))
void ukf_kernel(const float* __restrict__ yg, const float* __restrict__ ug,
                const float* __restrict__ z0g, const float* __restrict__ P0g,
                float* __restrict__ outg)
{
    const int tid = blockIdx.x*64 + threadIdx.x;

    DECL(A) DECL(B)
    LOAD(A, tid) LOAD(B, tid + BB/2)

    float2 ay_ = *reinterpret_cast<const float2*>(A_yb);
    float2 by_ = *reinterpret_cast<const float2*>(B_yb);
    {
        float2 t2;
        t2 = *reinterpret_cast<const float2*>(A_yb + 2); A_yn0 = t2.x; A_yn1 = t2.y;
        t2 = *reinterpret_cast<const float2*>(B_yb + 2); B_yn0 = t2.x; B_yn1 = t2.y;
    }
    A_un = A_ub[0];
    B_un = B_ub[0];

    // ---- t = 0 (no dynamics; diag consts = CJ) ----
    CHOL(A) CHOL(B)
    PRED0(A) PRED0(B)
    UPDATE(A, ay_.x, ay_.y, CJ, CJ, CJ)
    UPDATE(B, by_.x, by_.y, CJ, CJ, CJ)
    STOREZ(A, 0) STOREZ(B, 0)

    // ---- main loop t = 1..255, two independent filters interleaved ----
    #pragma unroll 1
    for (int t = 1; t < TT; ++t) {
        float ay0 = A_yn0, ay1 = A_yn1, au = A_un;
        float by0 = B_yn0, by1 = B_yn1, bu = B_un;
        int tn = (t+1 < TT) ? (t+1) : (TT-1);
        {
            float2 t2;
            t2 = *reinterpret_cast<const float2*>(A_yb + 2*tn); A_yn0 = t2.x; A_yn1 = t2.y;
            t2 = *reinterpret_cast<const float2*>(B_yb + 2*tn); B_yn0 = t2.x; B_yn1 = t2.y;
        }
        A_un = A_ub[t];
        B_un = B_ub[t];

        CHOL(A) CHOL(B)
        PRED(A, au) PRED(B, bu)
        UPDATE(A, ay0, ay1, CB00, CB11, CB22)
        UPDATE(B, by0, by1, CB00, CB11, CB22)
        STOREZ(A, t) STOREZ(B, t)
    }
}

extern "C" void kernel_launch(void* const* d_in, const int* in_sizes, int n_in,
                              void* d_out, int out_size, void* d_ws, size_t ws_size,
                              hipStream_t stream) {
    const float* y  = (const float*)d_in[0];   // (B,T,NY)
    const float* u  = (const float*)d_in[1];   // (B,T)
    const float* z0 = (const float*)d_in[2];   // (B,N)
    const float* P0 = (const float*)d_in[3];   // (B,N,N)
    float* out = (float*)d_out;                // (B,T,N)

    ukf_kernel<<<dim3((BB/2)/64), dim3(64), 0, stream>>>(y, u, z0, P0, out);
}

// Round 10
// 229.493 us; speedup vs baseline: 1.0025x; 1.0025x over previous
//
#include <hip/hip_runtime.h>
#include <math.h>

#ifndef __has_builtin
#define __has_builtin(x) 0
#endif

__device__ __forceinline__ float fsqrt(float x){
#if __has_builtin(__builtin_amdgcn_sqrtf)
    return __builtin_amdgcn_sqrtf(x);
#else
    return sqrtf(x);
#endif
}
__device__ __forceinline__ float frsqrt(float x){
#if __has_builtin(__builtin_amdgcn_rsqf)
    return __builtin_amdgcn_rsqf(x);
#else
    return 1.0f/sqrtf(x);
#endif
}
__device__ __forceinline__ float frcp(float x){
#if __has_builtin(__builtin_amdgcn_rcpf)
    return __builtin_amdgcn_rcpf(x);
#else
    return 1.0f/x;
#endif
}

namespace {
constexpr int TT = 256;
constexpr int BB = 16384;
constexpr float DT  = 0.05f, CD = 0.25f, AP = 0.1f, AV = 0.1f;
constexpr float CJ  = 2.56e-6f;              // CUT*JIT
constexpr float CVV = 1.0f - DT*CD;          // 0.9875
constexpr float WC0 = 1.7975f;
constexpr float W2  = 0.390625f;             // 2*WI ; CUT*W2 == 1.0 exactly
constexpr float WA  = 2.57875f;              // WC0 + 4WI
constexpr float WAC = 6.6016f;               // CUT*WA
constexpr float WCC = 4.6016f;               // CUT*WC0
constexpr float W2E = 0.1171875f;            // W2*0.3
constexpr float RSG = 0.00640512f;           // CUT*(Rd + 2*JIT)
constexpr float CQ2C = 1.53125f;             // CUT*CQ2
constexpr float CB00 = 3.072e-5f;            // CUT*(Q00 + 2JIT)
constexpr float CB11 = 2.6112e-4f;           // CUT*(Q11 + 2JIT)
constexpr float CB22 = 1.024e-5f;            // CUT*(predJIT + Q22 + 2JIT)
constexpr float HCUT = 1.28f;                // 0.5*CUT
constexpr float CUTc = 2.56f;
}

#define DECL(S) \
  float S##_z0,S##_z1,S##_z2,S##_z3, \
        S##_P00,S##_P01,S##_P02,S##_P03,S##_P11,S##_P12,S##_P13,S##_P22,S##_P23,S##_P33, \
        S##_g00,S##_g10,S##_g20,S##_g30,S##_g11,S##_g21,S##_g31,S##_g22,S##_g32,S##_g33, \
        S##_X00,S##_X01,S##_Xp,S##_Xm,S##_D10,S##_q,S##_D00,S##_D01,S##_D11,S##_D12,S##_D13, \
        S##_yn0,S##_yn1,S##_un; \
  const float *S##_yb, *S##_ub; float *S##_ob;

#define LOAD(S, bidx) { \
  const int b_ = (bidx); \
  S##_z0 = z0g[b_*4+0]; S##_z1 = z0g[b_*4+1]; S##_z2 = z0g[b_*4+2]; S##_z3 = z0g[b_*4+3]; \
  const float* Pb_ = P0g + (size_t)b_*16; \
  S##_P00 = CUTc*Pb_[0]; \
  S##_P01 = HCUT*(Pb_[1]+Pb_[4]); \
  S##_P02 = HCUT*(Pb_[2]+Pb_[8]); \
  S##_P03 = HCUT*(Pb_[3]+Pb_[12]); \
  S##_P11 = CUTc*Pb_[5]; \
  S##_P12 = HCUT*(Pb_[6]+Pb_[9]); \
  S##_P13 = HCUT*(Pb_[7]+Pb_[13]); \
  S##_P22 = CUTc*Pb_[10]; \
  S##_P23 = HCUT*(Pb_[11]+Pb_[14]); \
  S##_P33 = CUTc*Pb_[15]; \
  S##_yb = yg + (size_t)b_*TT*2; \
  S##_ub = ug + (size_t)b_*TT; \
  S##_ob = outg + (size_t)b_*TT*4; }

// G = chol(Pc + CJ*I)
#define CHOL(S) { \
  float a00_ = S##_P00 + CJ; \
  float r0_  = frsqrt(a00_); \
  S##_g00 = a00_*r0_; \
  S##_g10 = S##_P01*r0_; \
  S##_g20 = S##_P02*r0_; \
  S##_g30 = S##_P03*r0_; \
  float a11_ = fmaf(-S##_g10,S##_g10, S##_P11 + CJ); \
  float r1_  = frsqrt(a11_); \
  S##_g11 = a11_*r1_; \
  S##_g21 = fmaf(-S##_g20,S##_g10, S##_P12)*r1_; \
  S##_g31 = fmaf(-S##_g30,S##_g10, S##_P13)*r1_; \
  float a22_ = fmaf(-S##_g21,S##_g21, fmaf(-S##_g20,S##_g20, S##_P22 + CJ)); \
  float r2_  = frsqrt(a22_); \
  S##_g22 = a22_*r2_; \
  S##_g32 = fmaf(-S##_g31,S##_g21, fmaf(-S##_g30,S##_g20, S##_P23))*r2_; \
  float a33_ = fmaf(-S##_g32,S##_g32, fmaf(-S##_g31,S##_g31, fmaf(-S##_g30,S##_g30, S##_P33 + CJ))); \
  S##_g33 = fsqrt(a33_); }

#define PRED0(S) { \
  S##_X00=S##_z0; S##_X01=S##_z1; \
  S##_Xp=S##_z1+S##_g10; S##_Xm=S##_z1-S##_g10; \
  S##_D10=S##_g10; S##_q=0.0f; \
  S##_D00=S##_g00; S##_D01=0.0f; S##_D11=S##_g11; S##_D12=0.0f; S##_D13=0.0f; }

#define PRED(S, uu) { \
  float w_  = S##_z0*S##_z0; \
  float zc_ = w_*S##_z0; \
  S##_X00 = fmaf(DT, S##_z1, S##_z0); \
  float ac_ = fmaf(-CD, S##_z1, (uu)); \
  ac_ = fmaf(-S##_z2, S##_z0, ac_); \
  ac_ = fmaf(-S##_z3, zc_, ac_); \
  S##_X01 = fmaf(DT, ac_, S##_z1); \
  float pp_ = S##_z0+S##_g00, pm_ = S##_z0-S##_g00; \
  float vp_ = S##_z1+S##_g10, vm_ = S##_z1-S##_g10; \
  float kp_ = S##_z2+S##_g20, km_ = S##_z2-S##_g20; \
  float aP_ = S##_z3+S##_g30, aM_ = S##_z3-S##_g30; \
  float cp3_ = (pp_*pp_)*pp_, cm3_ = (pm_*pm_)*pm_; \
  float accp_ = fmaf(-CD, vp_, (uu)); accp_ = fmaf(-kp_,pp_,accp_); accp_ = fmaf(-aP_,cp3_,accp_); \
  S##_Xp = fmaf(DT, accp_, vp_); \
  float accm_ = fmaf(-CD, vm_, (uu)); accm_ = fmaf(-km_,pm_,accm_); accm_ = fmaf(-aM_,cm3_,accm_); \
  S##_Xm = fmaf(DT, accm_, vm_); \
  S##_D10 = 0.5f*(S##_Xp - S##_Xm); \
  S##_q   = fmaf(0.5f, S##_Xp + S##_Xm, -S##_X01); \
  S##_D00 = fmaf(DT, S##_g10, S##_g00); \
  S##_D01 = DT*S##_g11; \
  float ha_ = fmaf(S##_g31, zc_, S##_g21*S##_z0); \
  S##_D11 = fmaf(CVV, S##_g11, -(DT*ha_)); \
  float hb_ = fmaf(S##_g32, zc_, S##_g22*S##_z0); \
  S##_D12 = -(DT*hb_); \
  S##_D13 = -(DT*(S##_g33*zc_)); }

#define UPDATE(S, y0, y1, QA, QB, QC) { \
  float eps_c = -W2*S##_q; \
  float eps_a = S##_q + eps_c; \
  float zp1 = fmaf(W2, S##_q, S##_X01); \
  float w0 = S##_X00*S##_X00, w1 = S##_X01*S##_X01; \
  float apx = AP*S##_X00, avx = AV*S##_X01; \
  float Y00 = fmaf(apx, w0, S##_X00); \
  float Y01 = fmaf(avx, w1, S##_X01); \
  float cp = fmaf(0.3f, w0, 1.0f); \
  float cv = fmaf(0.3f, w1, 1.0f); \
  float e3p = 0.3f*S##_X00, e3v = 0.3f*S##_X01; \
  float w2e3p = W2E*S##_X00; \
  float D00sq = S##_D00*S##_D00, D01sq = S##_D01*S##_D01; \
  float SD0 = D00sq + D01sq; \
  float yp0 = fmaf(w2e3p, SD0, Y00); \
  float ec0 = Y00 - yp0; \
  float xi0 = fmaf(e3p, D00sq, ec0); \
  float xi1 = fmaf(e3p, D01sq, ec0); \
  float Od00 = S##_D00*fmaf(AP, D00sq, cp); \
  float Od01 = S##_D01*fmaf(AP, D01sq, cp); \
  float sp = S##_Xp*S##_Xp, sm = S##_Xm*S##_Xm; \
  float Yp = fmaf(AV*S##_Xp, sp, S##_Xp); \
  float Ym = fmaf(AV*S##_Xm, sm, S##_Xm); \
  float qy = fmaf(0.5f, Yp + Ym, -Y01); \
  float Q0 = 0.5f*(Yp - Ym); \
  float D11sq = S##_D11*S##_D11, D12sq = S##_D12*S##_D12, D13sq = S##_D13*S##_D13; \
  float SD1 = (D11sq + D12sq) + D13sq; \
  float inner = fmaf(e3v, SD1, qy); \
  float yp1 = fmaf(W2, inner, Y01); \
  float ec1 = Y01 - yp1; \
  float et0 = qy + ec1; \
  float et1 = fmaf(e3v, D11sq, ec1); \
  float et2 = fmaf(e3v, D12sq, ec1); \
  float et3 = fmaf(e3v, D13sq, ec1); \
  float Q1 = S##_D11*fmaf(AV, D11sq, cv); \
  float Q2 = S##_D12*fmaf(AV, D12sq, cv); \
  float Q3 = S##_D13*fmaf(AV, D13sq, cv); \
  float et23 = et2 + et3; \
  float Ts00 = fmaf(Od00,Od00, xi0*xi0); \
  Ts00 = fmaf(xi1,xi1,Ts00); Ts00 = fmaf(Od01,Od01,Ts00); \
  float s00 = fmaf(WAC, ec0*ec0, Ts00); \
  float Ts01 = fmaf(Od00, Q0, xi0*et0); \
  Ts01 = fmaf(xi1, et1, Ts01); Ts01 = fmaf(Od01, Q1, Ts01); \
  Ts01 = fmaf(ec0, et23, Ts01); \
  float s01 = fmaf(WCC, ec0*ec1, Ts01); \
  float Ts11 = fmaf(Q0,Q0, et0*et0); \
  Ts11 = fmaf(et1,et1,Ts11); Ts11 = fmaf(Q1,Q1,Ts11); \
  Ts11 = fmaf(et2,et2,Ts11); Ts11 = fmaf(Q2,Q2,Ts11); \
  Ts11 = fmaf(et3,et3,Ts11); Ts11 = fmaf(Q3,Q3,Ts11); \
  float s11 = fmaf(WCC, ec1*ec1, Ts11); \
  float pz00 = fmaf(S##_D01, Od01, S##_D00*Od00); \
  float pz01 = fmaf(S##_D01, Q1, S##_D00*Q0); \
  float Tp10 = fmaf(S##_D10, Od00, eps_a*xi0); \
  Tp10 = fmaf(eps_c, xi1, Tp10); Tp10 = fmaf(S##_D11, Od01, Tp10); \
  float pz10 = fmaf(-WA, S##_q*ec0, Tp10); \
  float et123 = et1 + et23; \
  float Tp11 = fmaf(S##_D10, Q0, eps_a*et0); \
  Tp11 = fmaf(eps_c, et123, Tp11); \
  Tp11 = fmaf(S##_D11, Q1, Tp11); \
  Tp11 = fmaf(S##_D12, Q2, Tp11); \
  Tp11 = fmaf(S##_D13, Q3, Tp11); \
  float pz11 = fmaf(-WC0, S##_q*ec1, Tp11); \
  float pz20 = fmaf(S##_g21, Od01, S##_g20*Od00); \
  float pz30 = fmaf(S##_g31, Od01, S##_g30*Od00); \
  float pz21 = fmaf(S##_g21, Q1, S##_g20*Q0); pz21 = fmaf(S##_g22, Q2, pz21); \
  float pz31 = fmaf(S##_g31, Q1, S##_g30*Q0); pz31 = fmaf(S##_g32, Q2, pz31); \
  pz31 = fmaf(S##_g33, Q3, pz31); \
  float sg00 = s00 + RSG, sg11 = s11 + RSG; \
  float det = fmaf(sg00, sg11, -(s01*s01)); \
  float idet = frcp(det); \
  float i00 = sg11*idet, i01 = -(s01*idet), i11 = sg00*idet; \
  float K00 = fmaf(pz01,i01, pz00*i00), K01 = fmaf(pz01,i11, pz00*i01); \
  float K10 = fmaf(pz11,i01, pz10*i00), K11 = fmaf(pz11,i11, pz10*i01); \
  float K20 = fmaf(pz21,i01, pz20*i00), K21 = fmaf(pz21,i11, pz20*i01); \
  float K30 = fmaf(pz31,i01, pz30*i00), K31 = fmaf(pz31,i11, pz30*i01); \
  float nu0 = (y0) - yp0, nu1 = (y1) - yp1; \
  S##_z0 = fmaf(K00,nu0, fmaf(K01,nu1, S##_X00)); \
  S##_z1 = fmaf(K10,nu0, fmaf(K11,nu1, zp1)); \
  S##_z2 = fmaf(K20,nu0, fmaf(K21,nu1, S##_z2)); \
  S##_z3 = fmaf(K30,nu0, fmaf(K31,nu1, S##_z3)); \
  float B00p = fmaf(S##_D01,S##_D01, fmaf(S##_D00,S##_D00, (QA))); \
  S##_P00 = fmaf(-K00,pz00, fmaf(-K01,pz01, B00p)); \
  float B01p = fmaf(S##_D01, S##_D11, S##_D00*S##_D10); \
  S##_P01 = fmaf(-K00,pz10, fmaf(-K01,pz11, B01p)); \
  float B02p = fmaf(S##_D01, S##_g21, S##_D00*S##_g20); \
  S##_P02 = fmaf(-K00,pz20, fmaf(-K01,pz21, B02p)); \
  float B03p = fmaf(S##_D01, S##_g31, S##_D00*S##_g30); \
  S##_P03 = fmaf(-K00,pz30, fmaf(-K01,pz31, B03p)); \
  float TB11 = fmaf(S##_D10,S##_D10, (QB)); \
  TB11 = fmaf(S##_D11,S##_D11,TB11); TB11 = fmaf(S##_D12,S##_D12,TB11); TB11 = fmaf(S##_D13,S##_D13,TB11); \
  float B11p = fmaf(CQ2C, S##_q*S##_q, TB11); \
  S##_P11 = fmaf(-K10,pz10, fmaf(-K11,pz11, B11p)); \
  float B12p = fmaf(S##_D11,S##_g21, S##_D10*S##_g20); B12p = fmaf(S##_D12,S##_g22,B12p); \
  S##_P12 = fmaf(-K10,pz20, fmaf(-K11,pz21, B12p)); \
  float B13p = fmaf(S##_D11,S##_g31, S##_D10*S##_g30); B13p = fmaf(S##_D12,S##_g32,B13p); B13p = fmaf(S##_D13,S##_g33,B13p); \
  S##_P13 = fmaf(-K10,pz30, fmaf(-K11,pz31, B13p)); \
  S##_P22 = fmaf(-K20,pz20, fmaf(-K21,pz21, S##_P22 + (QC))); \
  S##_P23 = fmaf(-K20,pz30, fmaf(-K21,pz31, S##_P23)); \
  S##_P33 = fmaf(-K30,pz30, fmaf(-K31,pz31, S##_P33 + (QC))); }

#define STOREZ(S, t) { \
  *reinterpret_cast<float4*>(S##_ob + 4*(t)) = make_float4(S##_z0,S##_z1,S##_z2,S##_z3); }

// R9 lesson: waves_per_eu(1,1) raised the budget only to 132 VGPR and the
// allocator still spilled ~12 floats/step (WRITE_SIZE ~171MB vs 70MB ideal).
// amdgpu_num_vgpr is the authoritative per-kernel register request — bypasses
// the occupancy heuristic entirely. 384 >> peak live (~250) at full 2-filter
// interleave; occupancy stays 1 wave/SIMD (128 waves on 1024 SIMDs) regardless.
__global__
__attribute__((amdgpu_flat_work_group_size(64, 64)))
__attribute__((amdgpu_waves_per_eu(1, 1)))
__attribute__((amdgpu_num_vgpr(384)))
void ukf_kernel(const float* __restrict__ yg, const float* __restrict__ ug,
                const float* __restrict__ z0g, const float* __restrict__ P0g,
                float* __restrict__ outg)
{
    const int tid = blockIdx.x*64 + threadIdx.x;

    DECL(A) DECL(B)
    LOAD(A, tid) LOAD(B, tid + BB/2)

    float2 ay_ = *reinterpret_cast<const float2*>(A_yb);
    float2 by_ = *reinterpret_cast<const float2*>(B_yb);
    {
        float2 t2;
        t2 = *reinterpret_cast<const float2*>(A_yb + 2); A_yn0 = t2.x; A_yn1 = t2.y;
        t2 = *reinterpret_cast<const float2*>(B_yb + 2); B_yn0 = t2.x; B_yn1 = t2.y;
    }
    A_un = A_ub[0];
    B_un = B_ub[0];

    // ---- t = 0 (no dynamics; diag consts = CJ) ----
    CHOL(A) CHOL(B)
    PRED0(A) PRED0(B)
    UPDATE(A, ay_.x, ay_.y, CJ, CJ, CJ)
    UPDATE(B, by_.x, by_.y, CJ, CJ, CJ)
    STOREZ(A, 0) STOREZ(B, 0)

    // ---- main loop t = 1..255, two independent filters interleaved ----
    #pragma unroll 1
    for (int t = 1; t < TT; ++t) {
        float ay0 = A_yn0, ay1 = A_yn1, au = A_un;
        float by0 = B_yn0, by1 = B_yn1, bu = B_un;
        int tn = (t+1 < TT) ? (t+1) : (TT-1);
        {
            float2 t2;
            t2 = *reinterpret_cast<const float2*>(A_yb + 2*tn); A_yn0 = t2.x; A_yn1 = t2.y;
            t2 = *reinterpret_cast<const float2*>(B_yb + 2*tn); B_yn0 = t2.x; B_yn1 = t2.y;
        }
        A_un = A_ub[t];
        B_un = B_ub[t];

        CHOL(A) CHOL(B)
        PRED(A, au) PRED(B, bu)
        UPDATE(A, ay0, ay1, CB00, CB11, CB22)
        UPDATE(B, by0, by1, CB00, CB11, CB22)
        STOREZ(A, t) STOREZ(B, t)
    }
}

extern "C" void kernel_launch(void* const* d_in, const int* in_sizes, int n_in,
                              void* d_out, int out_size, void* d_ws, size_t ws_size,
                              hipStream_t stream) {
    const float* y  = (const float*)d_in[0];   // (B,T,NY)
    const float* u  = (const float*)d_in[1];   // (B,T)
    const float* z0 = (const float*)d_in[2];   // (B,N)
    const float* P0 = (const float*)d_in[3];   // (B,N,N)
    float* out = (float*)d_out;                // (B,T,N)

    ukf_kernel<<<dim3((BB/2)/64), dim3(64), 0, stream>>>(y, u, z0, P0, out);
}

// Round 11
// 127.913 us; speedup vs baseline: 1.7987x; 1.7941x over previous
//
#include <hip/hip_runtime.h>
#include <math.h>

#ifndef __has_builtin
#define __has_builtin(x) 0
#endif

__device__ __forceinline__ float fsqrt(float x){
#if __has_builtin(__builtin_amdgcn_sqrtf)
    return __builtin_amdgcn_sqrtf(x);
#else
    return sqrtf(x);
#endif
}
__device__ __forceinline__ float frsqrt(float x){
#if __has_builtin(__builtin_amdgcn_rsqf)
    return __builtin_amdgcn_rsqf(x);
#else
    return 1.0f/sqrtf(x);
#endif
}
__device__ __forceinline__ float frcp(float x){
#if __has_builtin(__builtin_amdgcn_rcpf)
    return __builtin_amdgcn_rcpf(x);
#else
    return 1.0f/x;
#endif
}

namespace {
constexpr int TT = 256;
constexpr int BB = 16384;
constexpr float DT  = 0.05f, CD = 0.25f, AP = 0.1f, AV = 0.1f;
constexpr float CJ  = 2.56e-6f;              // CUT*JIT
constexpr float CVV = 1.0f - DT*CD;          // 0.9875
constexpr float WC0 = 1.7975f;
constexpr float W2  = 0.390625f;             // 2*WI ; CUT*W2 == 1.0 exactly
constexpr float WA  = 2.57875f;              // WC0 + 4WI
constexpr float WAC = 6.6016f;               // CUT*WA
constexpr float WCC = 4.6016f;               // CUT*WC0
constexpr float W2E = 0.1171875f;            // W2*0.3
constexpr float RSG = 0.00640512f;           // CUT*(Rd + 2*JIT)
constexpr float CQ2C = 1.53125f;             // CUT*CQ2
constexpr float CB00 = 3.072e-5f;            // CUT*(Q00 + 2JIT)
constexpr float CB11 = 2.6112e-4f;           // CUT*(Q11 + 2JIT)
constexpr float CB22 = 1.024e-5f;            // CUT*(predJIT + Q22 + 2JIT)
constexpr float HCUT = 1.28f;                // 0.5*CUT
constexpr float CUTc = 2.56f;
}

// R6-R10 lesson (reverted): with grid <= CU count, wall time == per-wave
// serial time. 2 filters/wave doubles per-wave work; ILP recovers <=1.4x ->
// net >=1.43x WORSE. One filter per thread (R5 structure) is optimal.
__global__ __launch_bounds__(64)
void ukf_kernel(const float* __restrict__ yg, const float* __restrict__ ug,
                const float* __restrict__ z0g, const float* __restrict__ P0g,
                float* __restrict__ outg)
{
    const int b = blockIdx.x*64 + threadIdx.x;

    float z0v = z0g[b*4+0], z1v = z0g[b*4+1], z2v = z0g[b*4+2], z3v = z0g[b*4+3];
    const float* Pb = P0g + (size_t)b*16;
    // Pc = CUT * sym(P0)
    float P00 = CUTc*Pb[0];
    float P01 = HCUT*(Pb[1]+Pb[4]);
    float P02 = HCUT*(Pb[2]+Pb[8]);
    float P03 = HCUT*(Pb[3]+Pb[12]);
    float P11 = CUTc*Pb[5];
    float P12 = HCUT*(Pb[6]+Pb[9]);
    float P13 = HCUT*(Pb[7]+Pb[13]);
    float P22 = CUTc*Pb[10];
    float P23 = HCUT*(Pb[11]+Pb[14]);
    float P33 = CUTc*Pb[15];

    const float* yb = yg + (size_t)b*TT*2;
    const float* ub = ug + (size_t)b*TT;
    float*       ob = outg + (size_t)b*TT*4;

    float g00,g10,g20,g30,g11,g21,g31,g22,g32,g33;

    // G = chol(Pc + CJ*I)
    auto chol = [&](){
        float a00 = P00 + CJ;
        float r0  = frsqrt(a00);
        g00 = a00*r0;
        g10 = P01*r0;
        g20 = P02*r0;
        g30 = P03*r0;
        float a11 = fmaf(-g10,g10, P11 + CJ);
        float r1  = frsqrt(a11);
        g11 = a11*r1;
        g21 = fmaf(-g20,g10, P12)*r1;
        g31 = fmaf(-g30,g10, P13)*r1;
        float a22 = fmaf(-g21,g21, fmaf(-g20,g20, P22 + CJ));
        float r2  = frsqrt(a22);
        g22 = a22*r2;
        g32 = fmaf(-g31,g21, fmaf(-g30,g20, P23))*r2;
        float a33 = fmaf(-g32,g32, fmaf(-g31,g31, fmaf(-g30,g30, P33 + CJ)));
        g33 = fsqrt(a33);
    };

    // Measurement update; all B/pz/S quantities CUT-scaled; K exact.
    auto update = [&](float X00, float X01, float Xp, float Xm,
                      float D10, float q,
                      float D00, float D01, float D11, float D12, float D13,
                      float B00p,float B01p,float B02p,float B03p,float B11p,
                      float B12p,float B13p,float B22p,float B23p,float B33p,
                      float yv0, float yv1)
    {
        float eps_c = -W2*q;
        float eps_a = q + eps_c;
        float zp1   = fmaf(W2, q, X01);

        float w0 = X00*X00, w1 = X01*X01;
        float apx = AP*X00, avx = AV*X01;
        float Y00 = fmaf(apx, w0, X00);
        float Y01 = fmaf(avx, w1, X01);
        float cp  = fmaf(0.3f, w0, 1.0f);
        float cv  = fmaf(0.3f, w1, 1.0f);
        float e3p = 0.3f*X00, e3v = 0.3f*X01;
        float w2e3p = W2E*X00;

        float D00sq = D00*D00, D01sq = D01*D01;
        float SD0 = D00sq + D01sq;
        float yp0 = fmaf(w2e3p, SD0, Y00);
        float ec0 = Y00 - yp0;
        float xi0 = fmaf(e3p, D00sq, ec0);
        float xi1 = fmaf(e3p, D01sq, ec0);
        float Od00 = D00*fmaf(AP, D00sq, cp);
        float Od01 = D01*fmaf(AP, D01sq, cp);

        float sp = Xp*Xp, sm = Xm*Xm;
        float Yp = fmaf(AV*Xp, sp, Xp);
        float Ym = fmaf(AV*Xm, sm, Xm);
        float qy = fmaf(0.5f, Yp + Ym, -Y01);
        float Q0 = 0.5f*(Yp - Ym);

        float D11sq = D11*D11, D12sq = D12*D12, D13sq = D13*D13;
        float SD1 = (D11sq + D12sq) + D13sq;
        float inner = fmaf(e3v, SD1, qy);
        float yp1 = fmaf(W2, inner, Y01);
        float ec1 = Y01 - yp1;
        float et0 = qy + ec1;
        float et1 = fmaf(e3v, D11sq, ec1);
        float et2 = fmaf(e3v, D12sq, ec1);
        float et3 = fmaf(e3v, D13sq, ec1);
        float Q1 = D11*fmaf(AV, D11sq, cv);
        float Q2 = D12*fmaf(AV, D12sq, cv);
        float Q3 = D13*fmaf(AV, D13sq, cv);
        float et23 = et2 + et3;

        // S' = CUT*S — tree-reduced accumulators (shorter dep chains)
        float tA00 = fmaf(Od00,Od00, xi0*xi0);
        float tB00 = fmaf(Od01,Od01, xi1*xi1);
        float s00 = fmaf(WAC, ec0*ec0, tA00 + tB00);
        float tA01 = fmaf(Od00, Q0, xi0*et0);
        float tB01 = fmaf(Od01, Q1, xi1*et1);
        tB01 = fmaf(ec0, et23, tB01);
        float s01 = fmaf(WCC, ec0*ec1, tA01 + tB01);
        float tA11 = fmaf(et1,et1, et0*et0);
        tA11 = fmaf(et2,et2,tA11); tA11 = fmaf(et3,et3,tA11);
        float tB11 = fmaf(Q1,Q1, Q0*Q0);
        tB11 = fmaf(Q2,Q2,tB11); tB11 = fmaf(Q3,Q3,tB11);
        float s11 = fmaf(WCC, ec1*ec1, tA11 + tB11);

        // pz' = CUT*P_zy (CUT*W2 == 1 absorbs W2)
        float pz00 = fmaf(D01, Od01, D00*Od00);
        float pz01 = fmaf(D01, Q1, D00*Q0);
        float Tp10 = fmaf(D10, Od00, eps_a*xi0);
        Tp10 = fmaf(eps_c, xi1, Tp10); Tp10 = fmaf(D11, Od01, Tp10);
        float pz10 = fmaf(-WA, q*ec0, Tp10);
        float et123 = et1 + et23;
        float TpA = fmaf(D10, Q0, eps_a*et0);
        TpA = fmaf(eps_c, et123, TpA);
        float TpB = fmaf(D12, Q2, D11*Q1);
        TpB = fmaf(D13, Q3, TpB);
        float pz11 = fmaf(-WC0, q*ec1, TpA + TpB);
        float pz20 = fmaf(g21, Od01, g20*Od00);
        float pz30 = fmaf(g31, Od01, g30*Od00);
        float pz21 = fmaf(g21, Q1, g20*Q0); pz21 = fmaf(g22, Q2, pz21);
        float pz31 = fmaf(g31, Q1, g30*Q0); pz31 = fmaf(g32, Q2, pz31);
        pz31 = fmaf(g33, Q3, pz31);

        // K = pz' * (S')^-1 (true gain; CUT cancels)
        float sg00 = s00 + RSG, sg11 = s11 + RSG;
        float det  = fmaf(sg00, sg11, -(s01*s01));
        float idet = frcp(det);
        float i00 = sg11*idet, i01 = -(s01*idet), i11 = sg00*idet;
        float K00 = fmaf(pz01,i01, pz00*i00), K01 = fmaf(pz01,i11, pz00*i01);
        float K10 = fmaf(pz11,i01, pz10*i00), K11 = fmaf(pz11,i11, pz10*i01);
        float K20 = fmaf(pz21,i01, pz20*i00), K21 = fmaf(pz21,i11, pz20*i01);
        float K30 = fmaf(pz31,i01, pz30*i00), K31 = fmaf(pz31,i11, pz30*i01);

        float nu0 = yv0 - yp0, nu1 = yv1 - yp1;
        z0v = fmaf(K00,nu0, fmaf(K01,nu1, X00));
        z1v = fmaf(K10,nu0, fmaf(K11,nu1, zp1));
        z2v = fmaf(K20,nu0, fmaf(K21,nu1, z2v));
        z3v = fmaf(K30,nu0, fmaf(K31,nu1, z3v));

        // Pc_post = B' - K*pz'^T
        P00 = fmaf(-K00,pz00, fmaf(-K01,pz01, B00p));
        P01 = fmaf(-K00,pz10, fmaf(-K01,pz11, B01p));
        P02 = fmaf(-K00,pz20, fmaf(-K01,pz21, B02p));
        P03 = fmaf(-K00,pz30, fmaf(-K01,pz31, B03p));
        P11 = fmaf(-K10,pz10, fmaf(-K11,pz11, B11p));
        P12 = fmaf(-K10,pz20, fmaf(-K11,pz21, B12p));
        P13 = fmaf(-K10,pz30, fmaf(-K11,pz31, B13p));
        P22 = fmaf(-K20,pz20, fmaf(-K21,pz21, B22p));
        P23 = fmaf(-K20,pz30, fmaf(-K21,pz31, B23p));
        P33 = fmaf(-K30,pz30, fmaf(-K31,pz31, B33p));
    };

    // one full time step: chol + predict + update + store
    float* op = ob;
    auto step = [&](float uu, float yv0, float yv1){
        chol();
        // center dynamics
        float w  = z0v*z0v;
        float zc = w*z0v;                       // p^3 at center
        float X00 = fmaf(DT, z1v, z0v);
        float ac = fmaf(-CD, z1v, uu);
        ac = fmaf(-z2v, z0v, ac);
        ac = fmaf(-z3v, zc, ac);
        float X01 = fmaf(DT, ac, z1v);
        // col0 explicit propagation
        float pp = z0v+g00, pm = z0v-g00;
        float vp = z1v+g10, vm = z1v-g10;
        float kp = z2v+g20, km = z2v-g20;
        float aap = z3v+g30, aam = z3v-g30;
        float cp3 = (pp*pp)*pp, cm3 = (pm*pm)*pm;
        float accp = fmaf(-CD, vp, uu); accp = fmaf(-kp,pp,accp); accp = fmaf(-aap,cp3,accp);
        float Xp = fmaf(DT, accp, vp);
        float accm = fmaf(-CD, vm, uu); accm = fmaf(-km,pm,accm); accm = fmaf(-aam,cm3,accm);
        float Xm = fmaf(DT, accm, vm);
        float D10 = 0.5f*(Xp - Xm);
        float q   = fmaf(0.5f, Xp + Xm, -X00*0.0f - X01);  // q = 0.5(Xp+Xm) - X01
        // odd propagation closed forms
        float D00 = fmaf(DT, g10, g00);
        float D01 = DT*g11;
        float ha  = fmaf(g31, zc, g21*z0v);
        float D11 = fmaf(CVV, g11, -(DT*ha));
        float hb  = fmaf(g32, zc, g22*z0v);
        float D12 = -(DT*hb);
        float D13 = -(DT*(g33*zc));
        // B' = CUT*P_pred (+ folded consts)
        float B00p = fmaf(D01,D01, fmaf(D00,D00, CB00));
        float B01p = fmaf(D01, D11, D00*D10);
        float B02p = fmaf(D01, g21, D00*g20);
        float B03p = fmaf(D01, g31, D00*g30);
        float TB11a = fmaf(D11,D11, D10*D10);
        float TB11b = fmaf(D13,D13, D12*D12);
        float B11p = fmaf(CQ2C, q*q, (TB11a + TB11b) + CB11);
        float B12p = fmaf(D11,g21, D10*g20); B12p = fmaf(D12,g22,B12p);
        float B13p = fmaf(D11,g31, D10*g30); B13p = fmaf(D12,g32,B13p);
        B13p = fmaf(D13,g33,B13p);
        float B22p = P22 + CB22;
        float B23p = P23;
        float B33p = P33 + CB22;
        update(X00, X01, Xp, Xm, D10, q, D00, D01, D11, D12, D13,
               B00p,B01p,B02p,B03p,B11p,B12p,B13p,B22p,B23p,B33p, yv0, yv1);
        *reinterpret_cast<float4*>(op) = make_float4(z0v,z1v,z2v,z3v);
        op += 4;
    };

    // ---- prologue loads (all aligned: yb 16B, ub 8B) ----
    float4 y01 = *reinterpret_cast<const float4*>(yb);      // y[0], y[1]
    float2 u01 = *reinterpret_cast<const float2*>(ub);      // u[0], u[1]
    float4 y4  = *reinterpret_cast<const float4*>(yb + 4);  // y[2], y[3]
    float2 u2  = *reinterpret_cast<const float2*>(ub + 2);  // u[2], u[3]

    // ---- t = 0 (no dynamics; diag consts = CJ) ----
    chol();
    update(z0v, z1v, z1v+g10, z1v-g10,
           g10, 0.0f,
           g00, 0.0f, g11, 0.0f, 0.0f,
           P00+CJ, P01, P02, P03, P11+CJ, P12, P13, P22+CJ, P23, P33+CJ,
           y01.x, y01.y);
    *reinterpret_cast<float4*>(op) = make_float4(z0v,z1v,z2v,z3v);
    op += 4;

    // ---- t = 1 ----
    step(u01.x, y01.z, y01.w);
    float ucar = u01.y;                          // u[1], for step t=2

    // ---- main pairs t = 2..252 (step 2), 1-pair-ahead prefetch, no clamps ----
    const float* yq = yb + 8;                    // -> y[4]
    const float* uq = ub + 4;                    // -> u[4]
    #pragma unroll 1
    for (int t = 2; t < 254; t += 2) {
        float ya0 = y4.x, ya1 = y4.y, yb0 = y4.z, yb1 = y4.w;  // y[t], y[t+1]
        float up = ucar, uc = u2.x;                            // u[t-1], u[t]
        ucar = u2.y;                                           // u[t+1]
        y4 = *reinterpret_cast<const float4*>(yq);  yq += 4;   // y[t+2..t+3]
        u2 = *reinterpret_cast<const float2*>(uq);  uq += 2;   // u[t+2..t+3]
        step(up, ya0, ya1);
        step(uc, yb0, yb1);
    }

    // ---- peeled final pair t = 254, 255 (no loads) ----
    step(ucar, y4.x, y4.y);
    step(u2.x, y4.z, y4.w);
}

extern "C" void kernel_launch(void* const* d_in, const int* in_sizes, int n_in,
                              void* d_out, int out_size, void* d_ws, size_t ws_size,
                              hipStream_t stream) {
    const float* y  = (const float*)d_in[0];   // (B,T,NY)
    const float* u  = (const float*)d_in[1];   // (B,T)
    const float* z0 = (const float*)d_in[2];   // (B,N)
    const float* P0 = (const float*)d_in[3];   // (B,N,N)
    float* out = (float*)d_out;                // (B,T,N)

    ukf_kernel<<<dim3(BB/64), dim3(64), 0, stream>>>(y, u, z0, P0, out);
}